// Round 1
// baseline (75.255 us; speedup 1.0000x reference)
//
#include <hip/hip_runtime.h>

// SpatiallyVariantConvolution: out[b,c,y,x] = sum_{i,j} feat_pad[b,c,y+i,x+j] * ker[b,i,j,y,x]
// b=4, c=96, h=w=256, k=7, pad=3, fp32.

#define BATCH 4
#define CHAN 96
#define HH_ 256
#define WW_ 256
#define KS 7
#define PADR 3
#define TW 32            // tile width  (x)
#define TH 16            // tile height (y)
#define CG 4             // channels per LDS stage (float4)
#define NCQ (CHAN / CG)  // 24 channel-quads
#define HALO_W (TW + KS - 1)  // 38
#define HALO_H (TH + KS - 1)  // 22
#define STAGE_N (HALO_H * HALO_W * CG)  // 3344 floats = 13.1 KB
#define NTHR 256
#define SPT ((STAGE_N + NTHR - 1) / NTHR)  // 14

__global__ __launch_bounds__(NTHR, 2)
void svconv_kernel(const float* __restrict__ kernels,
                   const float* __restrict__ features,
                   float* __restrict__ out) {
    __shared__ float lds[STAGE_N];

    const int tid = threadIdx.x;
    const int xt = blockIdx.x;   // 0..7
    const int yt = blockIdx.y;   // 0..15
    const int b  = blockIdx.z;   // 0..3

    const int tx  = tid & (TW - 1);   // 0..31  (x within tile)
    const int yi  = tid >> 5;         // 0..7   (y-pair index)
    const int gx  = xt * TW + tx;     // global x
    const int ly0 = 2 * yi;           // local y of first owned pixel
    const int gy0 = yt * TH + ly0;    // global y of first owned pixel

    // ---- kernel taps for the thread's two pixels, held in VGPRs all kernel ----
    float kr[2][KS][KS];
#pragma unroll
    for (int s = 0; s < 2; ++s)
#pragma unroll
        for (int i = 0; i < KS; ++i)
#pragma unroll
            for (int j = 0; j < KS; ++j)
                kr[s][i][j] = kernels[((((size_t)b * KS + i) * KS + j) * HH_ + (gy0 + s)) * WW_ + gx];

    // ---- staging prefetch registers ----
    float rbuf[SPT];

    // issue global loads for channel-quad cq into rbuf (consumed next phase)
    auto stage_load = [&](int cq) {
        const int c0 = cq * CG;
#pragma unroll
        for (int t = 0; t < SPT; ++t) {
            const int idx = tid + NTHR * t;
            float v = 0.0f;
            if (idx < STAGE_N) {
                const int c   = idx & (CG - 1);
                const int pix = idx >> 2;
                const int rx  = pix % HALO_W;
                const int ry  = pix / HALO_W;
                const int fy  = yt * TH + ry - PADR;
                const int fx  = xt * TW + rx - PADR;
                if ((unsigned)fy < (unsigned)HH_ && (unsigned)fx < (unsigned)WW_)
                    v = features[(((size_t)b * CHAN + (c0 + c)) * HH_ + fy) * WW_ + fx];
            }
            rbuf[t] = v;
        }
    };

    stage_load(0);

    for (int cq = 0; cq < NCQ; ++cq) {
        __syncthreads();  // previous compute done; LDS free
        // write staged quad (idx is tid-linear -> consecutive dwords, conflict-free)
#pragma unroll
        for (int t = 0; t < SPT; ++t) {
            const int idx = tid + NTHR * t;
            if (idx < STAGE_N) lds[idx] = rbuf[t];
        }
        __syncthreads();

        // prefetch next quad; results not needed until next iteration's write phase,
        // so these loads stay in flight under the compute below.
        if (cq + 1 < NCQ) stage_load(cq + 1);

        const float4* lds4 = reinterpret_cast<const float4*>(lds);

        float acc[2][CG];
#pragma unroll
        for (int s = 0; s < 2; ++s)
#pragma unroll
            for (int q = 0; q < CG; ++q) acc[s][q] = 0.0f;

#pragma unroll
        for (int roff = 0; roff < KS + 1; ++roff) {  // 8 feature rows for the y-pair
            const int r = ly0 + roff;                 // LDS row (0..21)
            float4 w[KS];
#pragma unroll
            for (int rxo = 0; rxo < KS; ++rxo)
                w[rxo] = lds4[r * HALO_W + tx + rxo];
#pragma unroll
            for (int rxo = 0; rxo < KS; ++rxo) {
#pragma unroll
                for (int s = 0; s < 2; ++s) {
                    const int i = roff - s;  // tap row for output pixel s
                    if (i >= 0 && i < KS) {
                        const float k = kr[s][i][rxo];
                        acc[s][0] += w[rxo].x * k;
                        acc[s][1] += w[rxo].y * k;
                        acc[s][2] += w[rxo].z * k;
                        acc[s][3] += w[rxo].w * k;
                    }
                }
            }
        }

        // store this quad's outputs (coalesced across lanes: consecutive gx)
        const int c0 = cq * CG;
#pragma unroll
        for (int s = 0; s < 2; ++s)
#pragma unroll
            for (int q = 0; q < CG; ++q)
                out[(((size_t)b * CHAN + (c0 + q)) * HH_ + (gy0 + s)) * WW_ + gx] = acc[s][q];
    }
}

extern "C" void kernel_launch(void* const* d_in, const int* in_sizes, int n_in,
                              void* d_out, int out_size, void* d_ws, size_t ws_size,
                              hipStream_t stream) {
    const float* kernels  = (const float*)d_in[0];  // [4,7,7,256,256]
    const float* features = (const float*)d_in[1];  // [4,96,256,256]
    float* out = (float*)d_out;                     // [4,96,256,256]

    dim3 grid(WW_ / TW, HH_ / TH, BATCH);  // (8, 16, 4) = 512 blocks
    dim3 block(NTHR);
    svconv_kernel<<<grid, block, 0, stream>>>(kernels, features, out);
}